// Round 2
// baseline (798.116 us; speedup 1.0000x reference)
//
#include <hip/hip_runtime.h>
#include <hip/hip_fp16.h>
#include <math.h>

// ---------------------------------------------------------------------------
// GAT x3 + BN on MI355X.
//   setup (NO global atomics — R8 showed each device-scope atomic is an
//   uncached 32B-sector RMW at memory: 800k atomics = ~180us):
//     k_hist_lds:  64 blocks, private LDS histogram (packed u16, 100KB dyn
//                  LDS) + ea col sums; plane dumped coalesced.
//     k_scan_a/b/c: sum 64 planes -> exclusive scan -> per-(block,node)
//                  cursor bases.
//     k_scatter_lds: same edge partition; rank via LDS packed-u16 atomic;
//                  pos = cursorp[b][d]+rank; writes ONE 16B struct
//                  {src,dst,3xfp16 ea} per edge.
//   layer:  k_gemm2: h = BN(X)@W (W in LDS, 4x4 reg tile) -> bf16 h,
//                    fused al_s/al_d/es epilogue
//           k_alpha3: meta[e] = {src, exp(lrelu(als[src]+ald[dst]+ea.P))}
//           k_agg6: one wave per TWO nodes (R10). R9 post-mortem: agg4's
//                   uniform edge loads were already SMEM s_loads; the
//                   readlane rewrite added serial VALU latency (127->133).
//                   Real bottleneck is dependent-load LATENCY (HBM 11%,
//                   VALU 12%, nothing saturated). Fix: interleave two
//                   independent per-node chains per wave -> ~16 loads in
//                   flight; meta via ONE 8B s_load/edge; no cross-lane ops.
//           k_inter: BN finalize + zero stats + next layer's param (1 block)
//           k_bnapply_final: scale/shift in-block, apply -> out
// ---------------------------------------------------------------------------

#define NB 64  // blocks for hist/scatter (same partition in both)

struct __align__(16) Edge2 { int src; int dst; unsigned e01; unsigned e2; };

__device__ __forceinline__ unsigned short f2bf(float x) {
  unsigned u = __float_as_uint(x);
  unsigned r = (u + 0x7FFFu + ((u >> 16) & 1u)) >> 16;  // RNE
  return (unsigned short)r;
}
__device__ __forceinline__ float bf_lo(unsigned u) { return __uint_as_float(u << 16); }
__device__ __forceinline__ float bf_hi(unsigned u) { return __uint_as_float(u & 0xFFFF0000u); }

// 64 blocks; private LDS histogram (packed u16) + ea column sums
__global__ void k_hist_lds(const int* __restrict__ dst, const float* __restrict__ ea, int E,
                           int n, unsigned* __restrict__ hist32, float* __restrict__ ea_sum) {
  extern __shared__ unsigned cnt[];
  int nh = (n + 1) >> 1;
  for (int i = threadIdx.x; i < nh; i += blockDim.x) cnt[i] = 0u;
  __syncthreads();
  int tid = blockIdx.x * blockDim.x + threadIdx.x;
  int stride = gridDim.x * blockDim.x;
  float s0 = 0.f, s1 = 0.f, s2 = 0.f;
  for (int i = tid; i < E; i += stride) {
    int d = dst[i];
    atomicAdd(&cnt[d >> 1], 1u << ((d & 1) << 4));
    s0 += ea[i * 3 + 0]; s1 += ea[i * 3 + 1]; s2 += ea[i * 3 + 2];
  }
  for (int off = 32; off; off >>= 1) {
    s0 += __shfl_down(s0, off); s1 += __shfl_down(s1, off); s2 += __shfl_down(s2, off);
  }
  if ((threadIdx.x & 63) == 0) {
    atomicAdd(&ea_sum[0], s0); atomicAdd(&ea_sum[1], s1); atomicAdd(&ea_sum[2], s2);
  }
  __syncthreads();
  unsigned* plane = hist32 + (size_t)blockIdx.x * nh;
  for (int i = threadIdx.x; i < nh; i += blockDim.x) plane[i] = cnt[i];
}

__device__ __forceinline__ int wave_incl_scan(int x, int lane) {
  for (int off = 1; off < 64; off <<= 1) {
    int t = __shfl_up(x, off);
    if (lane >= off) x += t;
  }
  return x;
}

// phase A: sum NB planes -> per-block exclusive scan -> start[], block sums
__global__ __launch_bounds__(1024) void k_scan_a(const unsigned* __restrict__ hist32, int n,
                                                 int* __restrict__ start,
                                                 int* __restrict__ bsum) {
  __shared__ int wsum[16];
  int t = threadIdx.x, lane = t & 63, w = t >> 6;
  int i = blockIdx.x * 1024 + t;
  int nh = (n + 1) >> 1;
  int stride2 = nh * 2;
  const unsigned short* h16 = (const unsigned short*)hist32;
  int v = 0;
  if (i < n) {
    for (int r = 0; r < NB; ++r) v += h16[(size_t)r * stride2 + i];
  }
  int x = wave_incl_scan(v, lane);
  if (lane == 63) wsum[w] = x;
  __syncthreads();
  if (w == 0 && lane < 16) {
    int s = wsum[lane];
    for (int off = 1; off < 16; off <<= 1) {
      int u = __shfl_up(s, off);
      if (lane >= off) s += u;
    }
    wsum[lane] = s;
  }
  __syncthreads();
  int woff = w ? wsum[w - 1] : 0;
  if (i < n) start[i] = x - v + woff;
  if (t == 1023) bsum[blockIdx.x] = wsum[15];
}

__global__ void k_scan_b(int* __restrict__ bsum, int nb, int* __restrict__ start, int n) {
  int lane = threadIdx.x;  // 64
  int v = (lane < nb) ? bsum[lane] : 0;
  int x = wave_incl_scan(v, lane);
  if (lane < nb) bsum[lane] = x - v;
  if (lane == nb - 1) start[n] = x;
}

// phase C: finalize start; emit per-(block,node) cursor bases
__global__ void k_scan_c(int* __restrict__ start, const int* __restrict__ bsum,
                         const unsigned* __restrict__ hist32, int n,
                         int* __restrict__ cursorp) {
  int i = blockIdx.x * blockDim.x + threadIdx.x;
  if (i >= n) return;
  int nh = (n + 1) >> 1;
  int stride2 = nh * 2;
  const unsigned short* h16 = (const unsigned short*)hist32;
  int s = start[i] + bsum[i >> 10];
  start[i] = s;
  int run = s;
  for (int r = 0; r < NB; ++r) {
    cursorp[(size_t)r * n + i] = run;
    run += h16[(size_t)r * stride2 + i];
  }
}

// same 64-block edge partition as hist; rank via LDS packed-u16 atomic;
// writes one 16B struct per edge — NO global atomics.
__global__ void k_scatter_lds(const int* __restrict__ src, const int* __restrict__ dst,
                              const float* __restrict__ ea, int E, int n,
                              const int* __restrict__ cursorp, Edge2* __restrict__ edges) {
  extern __shared__ unsigned cnt[];
  int nh = (n + 1) >> 1;
  for (int i = threadIdx.x; i < nh; i += blockDim.x) cnt[i] = 0u;
  __syncthreads();
  const int* cur = cursorp + (size_t)blockIdx.x * n;
  int tid = blockIdx.x * blockDim.x + threadIdx.x;
  int stride = gridDim.x * blockDim.x;
  for (int i = tid; i < E; i += stride) {
    int d = dst[i];
    int sh = (d & 1) << 4;
    unsigned old = atomicAdd(&cnt[d >> 1], 1u << sh);
    int rank = (old >> sh) & 0xFFFF;
    int pos = cur[d] + rank;
    unsigned short h0 = __half_as_ushort(__float2half(ea[i * 3 + 0]));
    unsigned short h1 = __half_as_ushort(__float2half(ea[i * 3 + 1]));
    unsigned short h2 = __half_as_ushort(__float2half(ea[i * 3 + 2]));
    Edge2 e;
    e.src = src[i];
    e.dst = d;
    e.e01 = (unsigned)h0 | ((unsigned)h1 << 16);
    e.e2 = (unsigned)h2;
    edges[pos] = e;
  }
}

__device__ __forceinline__ void param_wave(const float* __restrict__ We,
                                           const float* __restrict__ ae,
                                           const float* __restrict__ ea_sum, float invE,
                                           float* __restrict__ P, int lane) {
  float a0 = ae[lane], a1 = ae[64 + lane];
  float p0 = We[0 * 128 + lane] * a0 + We[0 * 128 + 64 + lane] * a1;
  float p1 = We[1 * 128 + lane] * a0 + We[1 * 128 + 64 + lane] * a1;
  float p2 = We[2 * 128 + lane] * a0 + We[2 * 128 + 64 + lane] * a1;
  for (int off = 32; off; off >>= 1) {
    p0 += __shfl_down(p0, off); p1 += __shfl_down(p1, off); p2 += __shfl_down(p2, off);
  }
  if (lane == 0) {
    P[0] = p0; P[1] = p1; P[2] = p2;
    P[3] = ea_sum[0] * invE * p0 + ea_sum[1] * invE * p1 + ea_sum[2] * invE * p2;
  }
}

__global__ void k_param0(const float* __restrict__ We, const float* __restrict__ ae,
                         const float* __restrict__ ea_sum, float invE, float* __restrict__ P,
                         float* __restrict__ scale, float* __restrict__ shift,
                         float* __restrict__ colstats) {
  int t = threadIdx.x;
  if (t < 64) {
    param_wave(We, ae, ea_sum, invE, P, t);
  } else if (t < 192) {
    int c = t - 64;
    scale[c] = 1.f; shift[c] = 0.f;
    colstats[c] = 0.f; colstats[128 + c] = 0.f;
  }
}

__global__ void k_inter(const float* __restrict__ colstatsIn, const float* __restrict__ g,
                        const float* __restrict__ be, float invN,
                        float* __restrict__ scale, float* __restrict__ shift,
                        const float* __restrict__ WeN, const float* __restrict__ aeN,
                        const float* __restrict__ ea_sum, float invE, float* __restrict__ P,
                        float* __restrict__ colstats) {
  int t = threadIdx.x;
  if (t < 64) {
    param_wave(WeN, aeN, ea_sum, invE, P, t);
  } else if (t < 192) {
    int c = t - 64;
    float mu = colstatsIn[c] * invN;
    float var = colstatsIn[128 + c] * invN - mu * mu;
    var = var > 0.f ? var : 0.f;
    float sc = g[c] * rsqrtf(var + 1e-5f);
    scale[c] = sc;
    shift[c] = be[c] - mu * sc;
    colstats[c] = 0.f; colstats[128 + c] = 0.f;
  }
}

// h[N,128] = (X*bnsc+bnsh) @ W, stored as bf16 rows (256 B).  W in LDS,
// 32-row tiles, 4 rows x 4 cols per thread.  Fused al_s/al_d/es epilogue.
__global__ __launch_bounds__(256) void k_gemm2(
    const float* __restrict__ X, const float* __restrict__ Wm,
    const float* __restrict__ bnsc, const float* __restrict__ bnsh,
    const float* __restrict__ as, const float* __restrict__ ad,
    const float* __restrict__ P,
    unsigned* __restrict__ hb, float* __restrict__ al_s, float* __restrict__ al_d,
    float* __restrict__ es, int n) {
  __shared__ float wl[128 * 128];
  __shared__ float xs[32 * 128];
  int t = threadIdx.x;
  for (int i = t; i < 4096; i += 256) ((float4*)wl)[i] = ((const float4*)Wm)[i];
  int c32 = t & 31;
  int c4 = c32 << 2;
  int rq = t >> 5;
  int lane = t & 63;
  float4 av_s = *(const float4*)(as + c4);
  float4 av_d = *(const float4*)(ad + c4);
  float cself = P[3];
  int ntiles = (n + 31) >> 5;
  for (int tile = blockIdx.x; tile < ntiles; tile += gridDim.x) {
    int r0 = tile << 5;
    __syncthreads();
    for (int i = t; i < 1024; i += 256) {
      int rr = i >> 5, cc = i & 31;
      int g = r0 + rr;
      float4 v;
      if (g < n) {
        v = ((const float4*)(X + (size_t)g * 128))[cc];
        float4 sc = ((const float4*)bnsc)[cc];
        float4 sh = ((const float4*)bnsh)[cc];
        v.x = fmaf(v.x, sc.x, sh.x); v.y = fmaf(v.y, sc.y, sh.y);
        v.z = fmaf(v.z, sc.z, sh.z); v.w = fmaf(v.w, sc.w, sh.w);
      } else { v.x = v.y = v.z = v.w = 0.f; }
      ((float4*)xs)[i] = v;
    }
    __syncthreads();
    float4 acc[4];
    for (int r = 0; r < 4; ++r) { acc[r].x = acc[r].y = acc[r].z = acc[r].w = 0.f; }
    const float* xr = xs + (rq << 2) * 128;
#pragma unroll 4
    for (int k = 0; k < 128; ++k) {
      float4 w4 = ((const float4*)wl)[(k << 5) + c32];
#pragma unroll
      for (int r = 0; r < 4; ++r) {
        float xv = xr[r * 128 + k];
        acc[r].x = fmaf(xv, w4.x, acc[r].x);
        acc[r].y = fmaf(xv, w4.y, acc[r].y);
        acc[r].z = fmaf(xv, w4.z, acc[r].z);
        acc[r].w = fmaf(xv, w4.w, acc[r].w);
      }
    }
    int gbase = r0 + (rq << 2);
#pragma unroll
    for (int r = 0; r < 4; ++r) {
      int g = gbase + r;
      float4 o = acc[r];
      if (g < n) {
        unsigned u01 = ((unsigned)f2bf(o.y) << 16) | (unsigned)f2bf(o.x);
        unsigned u23 = ((unsigned)f2bf(o.w) << 16) | (unsigned)f2bf(o.z);
        uint2 uu = {u01, u23};
        *(uint2*)(hb + (size_t)g * 64 + (c32 << 1)) = uu;
      }
      float ps = o.x * av_s.x + o.y * av_s.y + o.z * av_s.z + o.w * av_s.w;
      float pd = o.x * av_d.x + o.y * av_d.y + o.z * av_d.z + o.w * av_d.w;
      for (int off = 16; off; off >>= 1) {
        ps += __shfl_xor(ps, off);
        pd += __shfl_xor(pd, off);
      }
      if ((lane & 31) == 0 && g < n) {
        al_s[g] = ps; al_d[g] = pd;
        float a = ps + pd + cself;
        a = a > 0.f ? a : 0.2f * a;
        es[g] = __expf(a);
      }
    }
  }
}

// flat per-edge: meta[e] = {src, exp(lrelu_0.2(al_s[src] + al_d[dst] + ea.P))}
__global__ __launch_bounds__(256) void k_alpha3(const int4* __restrict__ edges,
                                                const float* __restrict__ al_s,
                                                const float* __restrict__ al_d,
                                                const float* __restrict__ P,
                                                int2* __restrict__ meta, int E) {
  int i = blockIdx.x * blockDim.x + threadIdx.x;
  if (i >= E) return;
  int4 ev = edges[i];
  float e0 = __half2float(__ushort_as_half((unsigned short)(ev.z & 0xFFFF)));
  float e1 = __half2float(__ushort_as_half((unsigned short)(((unsigned)ev.z) >> 16)));
  float e2 = __half2float(__ushort_as_half((unsigned short)(ev.w & 0xFFFF)));
  float a = al_s[ev.x] + al_d[ev.y] + e0 * P[0] + e1 * P[1] + e2 * P[2];
  a = a > 0.f ? a : 0.2f * a;
  int2 mv;
  mv.x = ev.x;
  mv.y = __float_as_int(__expf(a));
  meta[i] = mv;
}

// One wave per TWO nodes (A = i, B = i+nw): two independent dependency
// chains per wave (~16 loads in flight vs 8).  Per edge: one 8B uniform
// s_load of {src,pexp} + one 256B row gather.  Joint predicated loop covers
// balanced + imbalanced degrees (masked slots read meta[0]/hb row 0 with
// pexp=0 -> contribute nothing, L1-hot).
__global__ __launch_bounds__(256) void k_agg6(const int2* __restrict__ meta,
                                              const int* __restrict__ start,
                                              const unsigned* __restrict__ hb,
                                              const float* __restrict__ es,
                                              const float* __restrict__ bias,
                                              float* __restrict__ y,
                                              float* __restrict__ colsum,
                                              float* __restrict__ colsumsq, int n) {
  int lane = threadIdx.x & 63;
  int w = threadIdx.x >> 6;
  int gw = (blockIdx.x * blockDim.x + threadIdx.x) >> 6;
  int nw = (gridDim.x * blockDim.x) >> 6;
  float2 b2 = ((const float2*)bias)[lane];
  float s0 = 0.f, s1 = 0.f, q0 = 0.f, q1 = 0.f;
  for (int iA = gw; iA < n; iA += 2 * nw) {
    int iB = iA + nw;
    int hasB = (iB < n) ? 1 : 0;
    // head loads for BOTH nodes issue together (independent chains)
    int a0 = __builtin_amdgcn_readfirstlane(start[iA]);
    int a1 = __builtin_amdgcn_readfirstlane(start[iA + 1]);
    int b0 = 0, b1 = 0;
    if (hasB) {
      b0 = __builtin_amdgcn_readfirstlane(start[iB]);
      b1 = __builtin_amdgcn_readfirstlane(start[iB + 1]);
    }
    float esA = es[iA];
    float esB = hasB ? es[iB] : 0.f;
    unsigned hvA = hb[(size_t)iA * 64 + lane];
    unsigned hvB = hb[(size_t)(hasB ? iB : iA) * 64 + lane];
    float AX0 = esA * bf_lo(hvA), AY0 = esA * bf_hi(hvA);
    float AX1 = 0.f, AY1 = 0.f;
    float BX0 = esB * bf_lo(hvB), BY0 = esB * bf_hi(hvB);
    float BX1 = 0.f, BY1 = 0.f;
    float paccA = 0.f, paccB = 0.f;
    int ea = a0, eb = b0;
    while (ea < a1 || eb < b1) {
      int nA = a1 - ea; nA = nA > 8 ? 8 : (nA < 0 ? 0 : nA);
      int nB = b1 - eb; nB = nB > 8 ? 8 : (nB < 0 ? 0 : nB);
      int sA[8], sB[8];
      float pA[8], pB[8];
#pragma unroll
      for (int k = 0; k < 8; ++k) {
        if (k < nA) { int2 m = meta[ea + k]; sA[k] = m.x; pA[k] = __int_as_float(m.y); }
        else { sA[k] = 0; pA[k] = 0.f; }
      }
#pragma unroll
      for (int k = 0; k < 8; ++k) {
        if (k < nB) { int2 m = meta[eb + k]; sB[k] = m.x; pB[k] = __int_as_float(m.y); }
        else { sB[k] = 0; pB[k] = 0.f; }
      }
      unsigned gA[8], gB[8];
#pragma unroll
      for (int k = 0; k < 8; ++k) gA[k] = hb[(size_t)sA[k] * 64 + lane];
#pragma unroll
      for (int k = 0; k < 8; ++k) gB[k] = hb[(size_t)sB[k] * 64 + lane];
#pragma unroll
      for (int k = 0; k < 8; ++k) {
        paccA += pA[k];
        float gx = bf_lo(gA[k]), gy = bf_hi(gA[k]);
        if (k & 1) { AX1 = fmaf(pA[k], gx, AX1); AY1 = fmaf(pA[k], gy, AY1); }
        else       { AX0 = fmaf(pA[k], gx, AX0); AY0 = fmaf(pA[k], gy, AY0); }
      }
#pragma unroll
      for (int k = 0; k < 8; ++k) {
        paccB += pB[k];
        float gx = bf_lo(gB[k]), gy = bf_hi(gB[k]);
        if (k & 1) { BX1 = fmaf(pB[k], gx, BX1); BY1 = fmaf(pB[k], gy, BY1); }
        else       { BX0 = fmaf(pB[k], gx, BX0); BY0 = fmaf(pB[k], gy, BY0); }
      }
      ea += nA;
      eb += nB;
    }
    {
      float inv = 1.0f / (esA + paccA + 1e-16f);
      float o0 = fmaf(AX0 + AX1, inv, b2.x);
      float o1 = fmaf(AY0 + AY1, inv, b2.y);
      o0 = o0 > 0.f ? o0 : 0.01f * o0;
      o1 = o1 > 0.f ? o1 : 0.01f * o1;
      float2 o2 = {o0, o1};
      ((float2*)(y + (size_t)iA * 128))[lane] = o2;
      s0 += o0; s1 += o1;
      q0 = fmaf(o0, o0, q0); q1 = fmaf(o1, o1, q1);
    }
    if (hasB) {
      float inv = 1.0f / (esB + paccB + 1e-16f);
      float o0 = fmaf(BX0 + BX1, inv, b2.x);
      float o1 = fmaf(BY0 + BY1, inv, b2.y);
      o0 = o0 > 0.f ? o0 : 0.01f * o0;
      o1 = o1 > 0.f ? o1 : 0.01f * o1;
      float2 o2 = {o0, o1};
      ((float2*)(y + (size_t)iB * 128))[lane] = o2;
      s0 += o0; s1 += o1;
      q0 = fmaf(o0, o0, q0); q1 = fmaf(o1, o1, q1);
    }
  }
  __shared__ float red[4][4][64];
  red[0][w][lane] = s0; red[1][w][lane] = s1; red[2][w][lane] = q0; red[3][w][lane] = q1;
  __syncthreads();
  if (w == 0) {
    for (int ww = 1; ww < 4; ++ww) {
      s0 += red[0][ww][lane]; s1 += red[1][ww][lane];
      q0 += red[2][ww][lane]; q1 += red[3][ww][lane];
    }
    atomicAdd(&colsum[2 * lane], s0);
    atomicAdd(&colsum[2 * lane + 1], s1);
    atomicAdd(&colsumsq[2 * lane], q0);
    atomicAdd(&colsumsq[2 * lane + 1], q1);
  }
}

// final BN: compute scale/shift from colstats in-block, then apply y -> out
__global__ __launch_bounds__(256) void k_bnapply_final(
    const float4* __restrict__ yin, const float* __restrict__ colstats,
    const float* __restrict__ g, const float* __restrict__ be, float invN,
    float4* __restrict__ yout, int total4) {
  __shared__ float sc_s[128], sh_s[128];
  int t = threadIdx.x;
  if (t < 128) {
    float mu = colstats[t] * invN;
    float var = colstats[128 + t] * invN - mu * mu;
    var = var > 0.f ? var : 0.f;
    float sc = g[t] * rsqrtf(var + 1e-5f);
    sc_s[t] = sc;
    sh_s[t] = be[t] - mu * sc;
  }
  __syncthreads();
  for (int i = blockIdx.x * blockDim.x + t; i < total4; i += gridDim.x * blockDim.x) {
    int c4 = (i & 31) << 2;
    float4 v = yin[i];
    v.x = fmaf(v.x, sc_s[c4 + 0], sh_s[c4 + 0]);
    v.y = fmaf(v.y, sc_s[c4 + 1], sh_s[c4 + 1]);
    v.z = fmaf(v.z, sc_s[c4 + 2], sh_s[c4 + 2]);
    v.w = fmaf(v.w, sc_s[c4 + 3], sh_s[c4 + 3]);
    yout[i] = v;
  }
}

extern "C" void kernel_launch(void* const* d_in, const int* in_sizes, int n_in,
                              void* d_out, int out_size, void* d_ws, size_t ws_size,
                              hipStream_t stream) {
  const float* x = (const float*)d_in[0];
  const int* eidx = (const int*)d_in[1];
  const float* ea = (const float*)d_in[3];
  const int H = 128;
  const int N = in_sizes[0] / H;
  const int E = in_sizes[1] / 2;
  const int* srcIdx = eidx;
  const int* dstIdx = eidx + E;
  const int nh = (N + 1) >> 1;

  char* ws = (char*)d_ws;
  size_t off = 0;
  auto alloc = [&](size_t bytes) -> void* {
    void* p = ws + off;
    off = (off + bytes + 255) & ~(size_t)255;
    return p;
  };
  Edge2* edges = (Edge2*)alloc((size_t)E * sizeof(Edge2));
  int2* meta = (int2*)alloc((size_t)E * sizeof(int2));  // {src, pexp}
  unsigned* hb = (unsigned*)alloc((size_t)N * 64 * sizeof(unsigned));  // bf16 h
  float* y = (float*)alloc((size_t)N * H * sizeof(float));
  float* al_s = (float*)alloc((size_t)N * sizeof(float));
  float* al_d = (float*)alloc((size_t)N * sizeof(float));
  float* es = (float*)alloc((size_t)N * sizeof(float));
  unsigned* hist32 = (unsigned*)alloc((size_t)NB * nh * sizeof(unsigned));
  int* cursorp = (int*)alloc((size_t)NB * N * sizeof(int));
  int* start = (int*)alloc((size_t)(N + 1) * sizeof(int));
  int* bsum = (int*)alloc(64 * sizeof(int));
  float* colstats = (float*)alloc(256 * sizeof(float));
  float* colsum = colstats;
  float* colsumsq = colstats + 128;
  float* scale = (float*)alloc(128 * sizeof(float));
  float* shift = (float*)alloc(128 * sizeof(float));
  float* ea_sum = (float*)alloc(64 * sizeof(float));
  float* P = (float*)alloc(16 * sizeof(float));

  const int nb = (N + 1023) / 1024;  // <= 64
  const float invE = 1.0f / (float)E;
  const float invN = 1.0f / (float)N;
  const size_t ldsBytes = (size_t)nh * sizeof(unsigned);  // 100 KB @ N=50k

  // ---- setup: CSR sort with LDS-only atomics ----
  hipMemsetAsync(ea_sum, 0, 64 * sizeof(float), stream);
  k_hist_lds<<<NB, 256, ldsBytes, stream>>>(dstIdx, ea, E, N, hist32, ea_sum);
  k_scan_a<<<nb, 1024, 0, stream>>>(hist32, N, start, bsum);
  k_scan_b<<<1, 64, 0, stream>>>(bsum, nb, start, N);
  k_scan_c<<<(N + 255) / 256, 256, 0, stream>>>(start, bsum, hist32, N, cursorp);
  k_scatter_lds<<<NB, 256, ldsBytes, stream>>>(srcIdx, dstIdx, ea, E, N, cursorp, edges);

  // layer parameter pointers
  const float* Wl[3]; const float* asl[3]; const float* adl[3]; const float* Wel[3];
  const float* ael[3]; const float* bl[3]; const float* gl[3]; const float* bel[3];
  for (int l = 0; l < 3; ++l) {
    Wl[l] = (const float*)d_in[4 + 8 * l + 0];
    asl[l] = (const float*)d_in[4 + 8 * l + 1];
    adl[l] = (const float*)d_in[4 + 8 * l + 2];
    Wel[l] = (const float*)d_in[4 + 8 * l + 3];
    ael[l] = (const float*)d_in[4 + 8 * l + 4];
    bl[l] = (const float*)d_in[4 + 8 * l + 5];
    gl[l] = (const float*)d_in[4 + 8 * l + 6];
    bel[l] = (const float*)d_in[4 + 8 * l + 7];
  }

  k_param0<<<1, 192, 0, stream>>>(Wel[0], ael[0], ea_sum, invE, P, scale, shift, colstats);

  const float* X = x;
  for (int l = 0; l < 3; ++l) {
    k_gemm2<<<512, 256, 0, stream>>>(X, Wl[l], scale, shift, asl[l], adl[l], P,
                                     hb, al_s, al_d, es, N);
    k_alpha3<<<(E + 255) / 256, 256, 0, stream>>>((const int4*)edges, al_s, al_d, P,
                                                  meta, E);
    k_agg6<<<2048, 256, 0, stream>>>(meta, start, hb, es, bl[l], y,
                                     colsum, colsumsq, N);
    if (l < 2) {
      k_inter<<<1, 192, 0, stream>>>(colstats, gl[l], bel[l], invN, scale, shift,
                                     Wel[l + 1], ael[l + 1], ea_sum, invE, P, colstats);
    }
    X = y;
  }
  k_bnapply_final<<<384, 256, 0, stream>>>((const float4*)y, colstats, gl[2], bel[2], invN,
                                           (float4*)d_out, N * 32);
}

// Round 3
// 753.713 us; speedup vs baseline: 1.0589x; 1.0589x over previous
//
#include <hip/hip_runtime.h>
#include <hip/hip_fp16.h>
#include <math.h>

// ---------------------------------------------------------------------------
// GAT x3 + BN on MI355X.
//   setup (NO global atomics — R8: each device-scope atomic is an uncached
//   32B-sector RMW at memory):
//     k_hist_lds / k_scan_a/b/c / k_scatter_lds: LDS-atomic CSR sort.
//   layer:  k_gemm2: h = BN(X)@W (W in LDS, 4x4 reg tile) -> bf16 h,
//                    fused al_s/al_d/es epilogue
//           k_alpha3: meta[e] = {src, exp(lrelu(als[src]+ald[dst]+ea.P))}
//           k_agg7 (R11): agg4 loop structure (the 127us best; R9/R10 ILP
//                   variants both regressed -> wave-ILP is NOT the limit;
//                   measured ~5 outstanding gathers/CU => per-CU L1 MSHR
//                   cap hypothesis). Change: row gathers via inline-asm
//                   global_load_dword ... sc0 (L1-bypass, L2-direct) so
//                   gather misses are not tracked by the CU L1. Meta via
//                   ONE uniform s_load_dwordx2 {src,pexp} per edge.
//           k_inter: BN finalize + zero stats + next layer's param (1 block)
//           k_bnapply_final: scale/shift in-block, apply -> out
// ---------------------------------------------------------------------------

#define NB 64  // blocks for hist/scatter (same partition in both)

struct __align__(16) Edge2 { int src; int dst; unsigned e01; unsigned e2; };

__device__ __forceinline__ unsigned short f2bf(float x) {
  unsigned u = __float_as_uint(x);
  unsigned r = (u + 0x7FFFu + ((u >> 16) & 1u)) >> 16;  // RNE
  return (unsigned short)r;
}
__device__ __forceinline__ float bf_lo(unsigned u) { return __uint_as_float(u << 16); }
__device__ __forceinline__ float bf_hi(unsigned u) { return __uint_as_float(u & 0xFFFF0000u); }

// 64 blocks; private LDS histogram (packed u16) + ea column sums
__global__ void k_hist_lds(const int* __restrict__ dst, const float* __restrict__ ea, int E,
                           int n, unsigned* __restrict__ hist32, float* __restrict__ ea_sum) {
  extern __shared__ unsigned cnt[];
  int nh = (n + 1) >> 1;
  for (int i = threadIdx.x; i < nh; i += blockDim.x) cnt[i] = 0u;
  __syncthreads();
  int tid = blockIdx.x * blockDim.x + threadIdx.x;
  int stride = gridDim.x * blockDim.x;
  float s0 = 0.f, s1 = 0.f, s2 = 0.f;
  for (int i = tid; i < E; i += stride) {
    int d = dst[i];
    atomicAdd(&cnt[d >> 1], 1u << ((d & 1) << 4));
    s0 += ea[i * 3 + 0]; s1 += ea[i * 3 + 1]; s2 += ea[i * 3 + 2];
  }
  for (int off = 32; off; off >>= 1) {
    s0 += __shfl_down(s0, off); s1 += __shfl_down(s1, off); s2 += __shfl_down(s2, off);
  }
  if ((threadIdx.x & 63) == 0) {
    atomicAdd(&ea_sum[0], s0); atomicAdd(&ea_sum[1], s1); atomicAdd(&ea_sum[2], s2);
  }
  __syncthreads();
  unsigned* plane = hist32 + (size_t)blockIdx.x * nh;
  for (int i = threadIdx.x; i < nh; i += blockDim.x) plane[i] = cnt[i];
}

__device__ __forceinline__ int wave_incl_scan(int x, int lane) {
  for (int off = 1; off < 64; off <<= 1) {
    int t = __shfl_up(x, off);
    if (lane >= off) x += t;
  }
  return x;
}

// phase A: sum NB planes -> per-block exclusive scan -> start[], block sums
__global__ __launch_bounds__(1024) void k_scan_a(const unsigned* __restrict__ hist32, int n,
                                                 int* __restrict__ start,
                                                 int* __restrict__ bsum) {
  __shared__ int wsum[16];
  int t = threadIdx.x, lane = t & 63, w = t >> 6;
  int i = blockIdx.x * 1024 + t;
  int nh = (n + 1) >> 1;
  int stride2 = nh * 2;
  const unsigned short* h16 = (const unsigned short*)hist32;
  int v = 0;
  if (i < n) {
    for (int r = 0; r < NB; ++r) v += h16[(size_t)r * stride2 + i];
  }
  int x = wave_incl_scan(v, lane);
  if (lane == 63) wsum[w] = x;
  __syncthreads();
  if (w == 0 && lane < 16) {
    int s = wsum[lane];
    for (int off = 1; off < 16; off <<= 1) {
      int u = __shfl_up(s, off);
      if (lane >= off) s += u;
    }
    wsum[lane] = s;
  }
  __syncthreads();
  int woff = w ? wsum[w - 1] : 0;
  if (i < n) start[i] = x - v + woff;
  if (t == 1023) bsum[blockIdx.x] = wsum[15];
}

__global__ void k_scan_b(int* __restrict__ bsum, int nb, int* __restrict__ start, int n) {
  int lane = threadIdx.x;  // 64
  int v = (lane < nb) ? bsum[lane] : 0;
  int x = wave_incl_scan(v, lane);
  if (lane < nb) bsum[lane] = x - v;
  if (lane == nb - 1) start[n] = x;
}

// phase C: finalize start; emit per-(block,node) cursor bases
__global__ void k_scan_c(int* __restrict__ start, const int* __restrict__ bsum,
                         const unsigned* __restrict__ hist32, int n,
                         int* __restrict__ cursorp) {
  int i = blockIdx.x * blockDim.x + threadIdx.x;
  if (i >= n) return;
  int nh = (n + 1) >> 1;
  int stride2 = nh * 2;
  const unsigned short* h16 = (const unsigned short*)hist32;
  int s = start[i] + bsum[i >> 10];
  start[i] = s;
  int run = s;
  for (int r = 0; r < NB; ++r) {
    cursorp[(size_t)r * n + i] = run;
    run += h16[(size_t)r * stride2 + i];
  }
}

// same 64-block edge partition as hist; rank via LDS packed-u16 atomic;
// writes one 16B struct per edge — NO global atomics.
__global__ void k_scatter_lds(const int* __restrict__ src, const int* __restrict__ dst,
                              const float* __restrict__ ea, int E, int n,
                              const int* __restrict__ cursorp, Edge2* __restrict__ edges) {
  extern __shared__ unsigned cnt[];
  int nh = (n + 1) >> 1;
  for (int i = threadIdx.x; i < nh; i += blockDim.x) cnt[i] = 0u;
  __syncthreads();
  const int* cur = cursorp + (size_t)blockIdx.x * n;
  int tid = blockIdx.x * blockDim.x + threadIdx.x;
  int stride = gridDim.x * blockDim.x;
  for (int i = tid; i < E; i += stride) {
    int d = dst[i];
    int sh = (d & 1) << 4;
    unsigned old = atomicAdd(&cnt[d >> 1], 1u << sh);
    int rank = (old >> sh) & 0xFFFF;
    int pos = cur[d] + rank;
    unsigned short h0 = __half_as_ushort(__float2half(ea[i * 3 + 0]));
    unsigned short h1 = __half_as_ushort(__float2half(ea[i * 3 + 1]));
    unsigned short h2 = __half_as_ushort(__float2half(ea[i * 3 + 2]));
    Edge2 e;
    e.src = src[i];
    e.dst = d;
    e.e01 = (unsigned)h0 | ((unsigned)h1 << 16);
    e.e2 = (unsigned)h2;
    edges[pos] = e;
  }
}

__device__ __forceinline__ void param_wave(const float* __restrict__ We,
                                           const float* __restrict__ ae,
                                           const float* __restrict__ ea_sum, float invE,
                                           float* __restrict__ P, int lane) {
  float a0 = ae[lane], a1 = ae[64 + lane];
  float p0 = We[0 * 128 + lane] * a0 + We[0 * 128 + 64 + lane] * a1;
  float p1 = We[1 * 128 + lane] * a0 + We[1 * 128 + 64 + lane] * a1;
  float p2 = We[2 * 128 + lane] * a0 + We[2 * 128 + 64 + lane] * a1;
  for (int off = 32; off; off >>= 1) {
    p0 += __shfl_down(p0, off); p1 += __shfl_down(p1, off); p2 += __shfl_down(p2, off);
  }
  if (lane == 0) {
    P[0] = p0; P[1] = p1; P[2] = p2;
    P[3] = ea_sum[0] * invE * p0 + ea_sum[1] * invE * p1 + ea_sum[2] * invE * p2;
  }
}

__global__ void k_param0(const float* __restrict__ We, const float* __restrict__ ae,
                         const float* __restrict__ ea_sum, float invE, float* __restrict__ P,
                         float* __restrict__ scale, float* __restrict__ shift,
                         float* __restrict__ colstats) {
  int t = threadIdx.x;
  if (t < 64) {
    param_wave(We, ae, ea_sum, invE, P, t);
  } else if (t < 192) {
    int c = t - 64;
    scale[c] = 1.f; shift[c] = 0.f;
    colstats[c] = 0.f; colstats[128 + c] = 0.f;
  }
}

__global__ void k_inter(const float* __restrict__ colstatsIn, const float* __restrict__ g,
                        const float* __restrict__ be, float invN,
                        float* __restrict__ scale, float* __restrict__ shift,
                        const float* __restrict__ WeN, const float* __restrict__ aeN,
                        const float* __restrict__ ea_sum, float invE, float* __restrict__ P,
                        float* __restrict__ colstats) {
  int t = threadIdx.x;
  if (t < 64) {
    param_wave(WeN, aeN, ea_sum, invE, P, t);
  } else if (t < 192) {
    int c = t - 64;
    float mu = colstatsIn[c] * invN;
    float var = colstatsIn[128 + c] * invN - mu * mu;
    var = var > 0.f ? var : 0.f;
    float sc = g[c] * rsqrtf(var + 1e-5f);
    scale[c] = sc;
    shift[c] = be[c] - mu * sc;
    colstats[c] = 0.f; colstats[128 + c] = 0.f;
  }
}

// h[N,128] = (X*bnsc+bnsh) @ W, stored as bf16 rows (256 B).  W in LDS,
// 32-row tiles, 4 rows x 4 cols per thread.  Fused al_s/al_d/es epilogue.
__global__ __launch_bounds__(256) void k_gemm2(
    const float* __restrict__ X, const float* __restrict__ Wm,
    const float* __restrict__ bnsc, const float* __restrict__ bnsh,
    const float* __restrict__ as, const float* __restrict__ ad,
    const float* __restrict__ P,
    unsigned* __restrict__ hb, float* __restrict__ al_s, float* __restrict__ al_d,
    float* __restrict__ es, int n) {
  __shared__ float wl[128 * 128];
  __shared__ float xs[32 * 128];
  int t = threadIdx.x;
  for (int i = t; i < 4096; i += 256) ((float4*)wl)[i] = ((const float4*)Wm)[i];
  int c32 = t & 31;
  int c4 = c32 << 2;
  int rq = t >> 5;
  int lane = t & 63;
  float4 av_s = *(const float4*)(as + c4);
  float4 av_d = *(const float4*)(ad + c4);
  float cself = P[3];
  int ntiles = (n + 31) >> 5;
  for (int tile = blockIdx.x; tile < ntiles; tile += gridDim.x) {
    int r0 = tile << 5;
    __syncthreads();
    for (int i = t; i < 1024; i += 256) {
      int rr = i >> 5, cc = i & 31;
      int g = r0 + rr;
      float4 v;
      if (g < n) {
        v = ((const float4*)(X + (size_t)g * 128))[cc];
        float4 sc = ((const float4*)bnsc)[cc];
        float4 sh = ((const float4*)bnsh)[cc];
        v.x = fmaf(v.x, sc.x, sh.x); v.y = fmaf(v.y, sc.y, sh.y);
        v.z = fmaf(v.z, sc.z, sh.z); v.w = fmaf(v.w, sc.w, sh.w);
      } else { v.x = v.y = v.z = v.w = 0.f; }
      ((float4*)xs)[i] = v;
    }
    __syncthreads();
    float4 acc[4];
    for (int r = 0; r < 4; ++r) { acc[r].x = acc[r].y = acc[r].z = acc[r].w = 0.f; }
    const float* xr = xs + (rq << 2) * 128;
#pragma unroll 4
    for (int k = 0; k < 128; ++k) {
      float4 w4 = ((const float4*)wl)[(k << 5) + c32];
#pragma unroll
      for (int r = 0; r < 4; ++r) {
        float xv = xr[r * 128 + k];
        acc[r].x = fmaf(xv, w4.x, acc[r].x);
        acc[r].y = fmaf(xv, w4.y, acc[r].y);
        acc[r].z = fmaf(xv, w4.z, acc[r].z);
        acc[r].w = fmaf(xv, w4.w, acc[r].w);
      }
    }
    int gbase = r0 + (rq << 2);
#pragma unroll
    for (int r = 0; r < 4; ++r) {
      int g = gbase + r;
      float4 o = acc[r];
      if (g < n) {
        unsigned u01 = ((unsigned)f2bf(o.y) << 16) | (unsigned)f2bf(o.x);
        unsigned u23 = ((unsigned)f2bf(o.w) << 16) | (unsigned)f2bf(o.z);
        uint2 uu = {u01, u23};
        *(uint2*)(hb + (size_t)g * 64 + (c32 << 1)) = uu;
      }
      float ps = o.x * av_s.x + o.y * av_s.y + o.z * av_s.z + o.w * av_s.w;
      float pd = o.x * av_d.x + o.y * av_d.y + o.z * av_d.z + o.w * av_d.w;
      for (int off = 16; off; off >>= 1) {
        ps += __shfl_xor(ps, off);
        pd += __shfl_xor(pd, off);
      }
      if ((lane & 31) == 0 && g < n) {
        al_s[g] = ps; al_d[g] = pd;
        float a = ps + pd + cself;
        a = a > 0.f ? a : 0.2f * a;
        es[g] = __expf(a);
      }
    }
  }
}

// flat per-edge: meta[e] = {src, exp(lrelu_0.2(al_s[src] + al_d[dst] + ea.P))}
__global__ __launch_bounds__(256) void k_alpha3(const int4* __restrict__ edges,
                                                const float* __restrict__ al_s,
                                                const float* __restrict__ al_d,
                                                const float* __restrict__ P,
                                                int2* __restrict__ meta, int E) {
  int i = blockIdx.x * blockDim.x + threadIdx.x;
  if (i >= E) return;
  int4 ev = edges[i];
  float e0 = __half2float(__ushort_as_half((unsigned short)(ev.z & 0xFFFF)));
  float e1 = __half2float(__ushort_as_half((unsigned short)(((unsigned)ev.z) >> 16)));
  float e2 = __half2float(__ushort_as_half((unsigned short)(ev.w & 0xFFFF)));
  float a = al_s[ev.x] + al_d[ev.y] + e0 * P[0] + e1 * P[1] + e2 * P[2];
  a = a > 0.f ? a : 0.2f * a;
  int2 mv;
  mv.x = ev.x;
  mv.y = __float_as_int(__expf(a));
  meta[i] = mv;
}

// One wave per node (agg4 structure = measured best).  Per edge: one uniform
// s_load_dwordx2 {src,pexp} + ONE row gather via inline-asm global_load
// with sc0 (L1-bypass -> not tracked by CU-L1 MSHRs; serviced by L2).
__global__ __launch_bounds__(256) void k_agg7(const int2* __restrict__ meta,
                                              const int* __restrict__ start,
                                              const unsigned* __restrict__ hb,
                                              const float* __restrict__ es,
                                              const float* __restrict__ bias,
                                              float* __restrict__ y,
                                              float* __restrict__ colsum,
                                              float* __restrict__ colsumsq, int n) {
  int lane = threadIdx.x & 63;
  int w = threadIdx.x >> 6;
  int gw = (blockIdx.x * blockDim.x + threadIdx.x) >> 6;
  int nw = (gridDim.x * blockDim.x) >> 6;
  float2 b2 = ((const float2*)bias)[lane];
  unsigned voff = (unsigned)(lane << 2);  // byte offset of this lane in a row
  float s0 = 0.f, s1 = 0.f, q0 = 0.f, q1 = 0.f;
  for (int i = gw; i < n; i += nw) {
    int e0 = __builtin_amdgcn_readfirstlane(start[i]);
    int e1 = __builtin_amdgcn_readfirstlane(start[i + 1]);
    float eself = es[i];
    unsigned hv = hb[(size_t)i * 64 + lane];
    float aX0 = eself * bf_lo(hv), aY0 = eself * bf_hi(hv);
    float aX1 = 0.f, aY1 = 0.f, aX2 = 0.f, aY2 = 0.f, aX3 = 0.f, aY3 = 0.f;
    float pacc = 0.f;
    int e = e0;
    for (; e + 8 <= e1; e += 8) {
      int sv[8]; float pv[8]; unsigned gv[8];
#pragma unroll
      for (int k = 0; k < 8; ++k) {
        int2 m = meta[e + k];          // uniform -> s_load_dwordx2
        sv[k] = m.x;
        pv[k] = __int_as_float(m.y);
      }
#pragma unroll
      for (int k = 0; k < 8; ++k) {
        const unsigned* rp = hb + (size_t)sv[k] * 64;  // uniform row base (SGPR pair)
        asm volatile("global_load_dword %0, %1, %2 sc0"
                     : "=v"(gv[k]) : "v"(voff), "s"(rp));
      }
      asm volatile("s_waitcnt vmcnt(0)"
                   : "+v"(gv[0]), "+v"(gv[1]), "+v"(gv[2]), "+v"(gv[3]),
                     "+v"(gv[4]), "+v"(gv[5]), "+v"(gv[6]), "+v"(gv[7]));
#pragma unroll
      for (int k = 0; k < 8; ++k) {
        float gx = bf_lo(gv[k]);
        float gy = bf_hi(gv[k]);
        pacc += pv[k];
        if ((k & 3) == 0) { aX0 = fmaf(pv[k], gx, aX0); aY0 = fmaf(pv[k], gy, aY0); }
        else if ((k & 3) == 1) { aX1 = fmaf(pv[k], gx, aX1); aY1 = fmaf(pv[k], gy, aY1); }
        else if ((k & 3) == 2) { aX2 = fmaf(pv[k], gx, aX2); aY2 = fmaf(pv[k], gy, aY2); }
        else { aX3 = fmaf(pv[k], gx, aX3); aY3 = fmaf(pv[k], gy, aY3); }
      }
    }
    for (; e < e1; ++e) {
      int2 m = meta[e];
      float pvs = __int_as_float(m.y);
      const unsigned* rp = hb + (size_t)m.x * 64;
      unsigned gvv;
      asm volatile("global_load_dword %0, %1, %2 sc0"
                   : "=v"(gvv) : "v"(voff), "s"(rp));
      asm volatile("s_waitcnt vmcnt(0)" : "+v"(gvv));
      pacc += pvs;
      aX0 = fmaf(pvs, bf_lo(gvv), aX0);
      aY0 = fmaf(pvs, bf_hi(gvv), aY0);
    }
    float inv = 1.0f / (eself + pacc + 1e-16f);
    float o0 = (aX0 + aX1) + (aX2 + aX3);
    float o1 = (aY0 + aY1) + (aY2 + aY3);
    o0 = fmaf(o0, inv, b2.x);
    o1 = fmaf(o1, inv, b2.y);
    o0 = o0 > 0.f ? o0 : 0.01f * o0;
    o1 = o1 > 0.f ? o1 : 0.01f * o1;
    float2 o2 = {o0, o1};
    ((float2*)(y + (size_t)i * 128))[lane] = o2;
    s0 += o0; s1 += o1;
    q0 = fmaf(o0, o0, q0); q1 = fmaf(o1, o1, q1);
  }
  __shared__ float red[4][4][64];
  red[0][w][lane] = s0; red[1][w][lane] = s1; red[2][w][lane] = q0; red[3][w][lane] = q1;
  __syncthreads();
  if (w == 0) {
    for (int ww = 1; ww < 4; ++ww) {
      s0 += red[0][ww][lane]; s1 += red[1][ww][lane];
      q0 += red[2][ww][lane]; q1 += red[3][ww][lane];
    }
    atomicAdd(&colsum[2 * lane], s0);
    atomicAdd(&colsum[2 * lane + 1], s1);
    atomicAdd(&colsumsq[2 * lane], q0);
    atomicAdd(&colsumsq[2 * lane + 1], q1);
  }
}

// final BN: compute scale/shift from colstats in-block, then apply y -> out
__global__ __launch_bounds__(256) void k_bnapply_final(
    const float4* __restrict__ yin, const float* __restrict__ colstats,
    const float* __restrict__ g, const float* __restrict__ be, float invN,
    float4* __restrict__ yout, int total4) {
  __shared__ float sc_s[128], sh_s[128];
  int t = threadIdx.x;
  if (t < 128) {
    float mu = colstats[t] * invN;
    float var = colstats[128 + t] * invN - mu * mu;
    var = var > 0.f ? var : 0.f;
    float sc = g[t] * rsqrtf(var + 1e-5f);
    sc_s[t] = sc;
    sh_s[t] = be[t] - mu * sc;
  }
  __syncthreads();
  for (int i = blockIdx.x * blockDim.x + t; i < total4; i += gridDim.x * blockDim.x) {
    int c4 = (i & 31) << 2;
    float4 v = yin[i];
    v.x = fmaf(v.x, sc_s[c4 + 0], sh_s[c4 + 0]);
    v.y = fmaf(v.y, sc_s[c4 + 1], sh_s[c4 + 1]);
    v.z = fmaf(v.z, sc_s[c4 + 2], sh_s[c4 + 2]);
    v.w = fmaf(v.w, sc_s[c4 + 3], sh_s[c4 + 3]);
    yout[i] = v;
  }
}

extern "C" void kernel_launch(void* const* d_in, const int* in_sizes, int n_in,
                              void* d_out, int out_size, void* d_ws, size_t ws_size,
                              hipStream_t stream) {
  const float* x = (const float*)d_in[0];
  const int* eidx = (const int*)d_in[1];
  const float* ea = (const float*)d_in[3];
  const int H = 128;
  const int N = in_sizes[0] / H;
  const int E = in_sizes[1] / 2;
  const int* srcIdx = eidx;
  const int* dstIdx = eidx + E;
  const int nh = (N + 1) >> 1;

  char* ws = (char*)d_ws;
  size_t off = 0;
  auto alloc = [&](size_t bytes) -> void* {
    void* p = ws + off;
    off = (off + bytes + 255) & ~(size_t)255;
    return p;
  };
  Edge2* edges = (Edge2*)alloc((size_t)E * sizeof(Edge2));
  int2* meta = (int2*)alloc((size_t)E * sizeof(int2));  // {src, pexp}
  unsigned* hb = (unsigned*)alloc((size_t)N * 64 * sizeof(unsigned));  // bf16 h
  float* y = (float*)alloc((size_t)N * H * sizeof(float));
  float* al_s = (float*)alloc((size_t)N * sizeof(float));
  float* al_d = (float*)alloc((size_t)N * sizeof(float));
  float* es = (float*)alloc((size_t)N * sizeof(float));
  unsigned* hist32 = (unsigned*)alloc((size_t)NB * nh * sizeof(unsigned));
  int* cursorp = (int*)alloc((size_t)NB * N * sizeof(int));
  int* start = (int*)alloc((size_t)(N + 1) * sizeof(int));
  int* bsum = (int*)alloc(64 * sizeof(int));
  float* colstats = (float*)alloc(256 * sizeof(float));
  float* colsum = colstats;
  float* colsumsq = colstats + 128;
  float* scale = (float*)alloc(128 * sizeof(float));
  float* shift = (float*)alloc(128 * sizeof(float));
  float* ea_sum = (float*)alloc(64 * sizeof(float));
  float* P = (float*)alloc(16 * sizeof(float));

  const int nb = (N + 1023) / 1024;  // <= 64
  const float invE = 1.0f / (float)E;
  const float invN = 1.0f / (float)N;
  const size_t ldsBytes = (size_t)nh * sizeof(unsigned);  // 100 KB @ N=50k

  // ---- setup: CSR sort with LDS-only atomics ----
  hipMemsetAsync(ea_sum, 0, 64 * sizeof(float), stream);
  k_hist_lds<<<NB, 256, ldsBytes, stream>>>(dstIdx, ea, E, N, hist32, ea_sum);
  k_scan_a<<<nb, 1024, 0, stream>>>(hist32, N, start, bsum);
  k_scan_b<<<1, 64, 0, stream>>>(bsum, nb, start, N);
  k_scan_c<<<(N + 255) / 256, 256, 0, stream>>>(start, bsum, hist32, N, cursorp);
  k_scatter_lds<<<NB, 256, ldsBytes, stream>>>(srcIdx, dstIdx, ea, E, N, cursorp, edges);

  // layer parameter pointers
  const float* Wl[3]; const float* asl[3]; const float* adl[3]; const float* Wel[3];
  const float* ael[3]; const float* bl[3]; const float* gl[3]; const float* bel[3];
  for (int l = 0; l < 3; ++l) {
    Wl[l] = (const float*)d_in[4 + 8 * l + 0];
    asl[l] = (const float*)d_in[4 + 8 * l + 1];
    adl[l] = (const float*)d_in[4 + 8 * l + 2];
    Wel[l] = (const float*)d_in[4 + 8 * l + 3];
    ael[l] = (const float*)d_in[4 + 8 * l + 4];
    bl[l] = (const float*)d_in[4 + 8 * l + 5];
    gl[l] = (const float*)d_in[4 + 8 * l + 6];
    bel[l] = (const float*)d_in[4 + 8 * l + 7];
  }

  k_param0<<<1, 192, 0, stream>>>(Wel[0], ael[0], ea_sum, invE, P, scale, shift, colstats);

  const float* X = x;
  for (int l = 0; l < 3; ++l) {
    k_gemm2<<<512, 256, 0, stream>>>(X, Wl[l], scale, shift, asl[l], adl[l], P,
                                     hb, al_s, al_d, es, N);
    k_alpha3<<<(E + 255) / 256, 256, 0, stream>>>((const int4*)edges, al_s, al_d, P,
                                                  meta, E);
    k_agg7<<<2048, 256, 0, stream>>>(meta, start, hb, es, bl[l], y,
                                     colsum, colsumsq, N);
    if (l < 2) {
      k_inter<<<1, 192, 0, stream>>>(colstats, gl[l], bel[l], invN, scale, shift,
                                     Wel[l + 1], ael[l + 1], ea_sum, invE, P, colstats);
    }
    X = y;
  }
  k_bnapply_final<<<384, 256, 0, stream>>>((const float4*)y, colstats, gl[2], bel[2], invN,
                                           (float4*)d_out, N * 32);
}

// Round 5
// 751.100 us; speedup vs baseline: 1.0626x; 1.0035x over previous
//
#include <hip/hip_runtime.h>
#include <hip/hip_fp16.h>
#include <math.h>

// ---------------------------------------------------------------------------
// GAT x3 + BN on MI355X.
//   setup (NO global atomics — R8: each device-scope atomic is an uncached
//   32B-sector RMW at memory):
//     k_hist_lds / k_scan_a/b/c / k_scatter_lds: LDS-atomic CSR sort.
//   layer:  k_gemm2: h = BN(X)@W (W in LDS, 4x4 reg tile) -> bf16 h,
//                    fused al_s/al_d/es epilogue
//           k_alpha3: meta[e] = {src, exp(lrelu(als[src]+ald[dst]+ea.P))}
//           k_agg9 (R13): 4-edges-per-gather. History: R9 (readlane) null,
//                   R10 (2-node ILP) null, R11 (sc0 L1-bypass) null, R12
//                   (asm vmcnt pipeline) NaN — reverted. Consistent model:
//                   per-CU service cap on divergent vector-mem INSTRUCTIONS
//                   (~32cy each), not wave ILP. k_agg9 fetches each 256B hb
//                   row with 16 lanes x uint4: lane-group g in {0..3} takes
//                   edge k+g -> 4 edges per gather instruction (4x fewer).
//                   Row/weight per group selected from uniform SGPR meta;
//                   8 accs/lane (cols 8*sub..8*sub+7); cross-group
//                   shfl_xor(16,32) combine once per node. Plain C++ only.
//           k_inter: BN finalize + zero stats + next layer's param (1 block)
//           k_bnapply_final: scale/shift in-block, apply -> out
// ---------------------------------------------------------------------------

#define NB 64  // blocks for hist/scatter (same partition in both)

struct __align__(16) Edge2 { int src; int dst; unsigned e01; unsigned e2; };

__device__ __forceinline__ unsigned short f2bf(float x) {
  unsigned u = __float_as_uint(x);
  unsigned r = (u + 0x7FFFu + ((u >> 16) & 1u)) >> 16;  // RNE
  return (unsigned short)r;
}
__device__ __forceinline__ float bf_lo(unsigned u) { return __uint_as_float(u << 16); }
__device__ __forceinline__ float bf_hi(unsigned u) { return __uint_as_float(u & 0xFFFF0000u); }

// 64 blocks; private LDS histogram (packed u16) + ea column sums
__global__ void k_hist_lds(const int* __restrict__ dst, const float* __restrict__ ea, int E,
                           int n, unsigned* __restrict__ hist32, float* __restrict__ ea_sum) {
  extern __shared__ unsigned cnt[];
  int nh = (n + 1) >> 1;
  for (int i = threadIdx.x; i < nh; i += blockDim.x) cnt[i] = 0u;
  __syncthreads();
  int tid = blockIdx.x * blockDim.x + threadIdx.x;
  int stride = gridDim.x * blockDim.x;
  float s0 = 0.f, s1 = 0.f, s2 = 0.f;
  for (int i = tid; i < E; i += stride) {
    int d = dst[i];
    atomicAdd(&cnt[d >> 1], 1u << ((d & 1) << 4));
    s0 += ea[i * 3 + 0]; s1 += ea[i * 3 + 1]; s2 += ea[i * 3 + 2];
  }
  for (int off = 32; off; off >>= 1) {
    s0 += __shfl_down(s0, off); s1 += __shfl_down(s1, off); s2 += __shfl_down(s2, off);
  }
  if ((threadIdx.x & 63) == 0) {
    atomicAdd(&ea_sum[0], s0); atomicAdd(&ea_sum[1], s1); atomicAdd(&ea_sum[2], s2);
  }
  __syncthreads();
  unsigned* plane = hist32 + (size_t)blockIdx.x * nh;
  for (int i = threadIdx.x; i < nh; i += blockDim.x) plane[i] = cnt[i];
}

__device__ __forceinline__ int wave_incl_scan(int x, int lane) {
  for (int off = 1; off < 64; off <<= 1) {
    int t = __shfl_up(x, off);
    if (lane >= off) x += t;
  }
  return x;
}

// phase A: sum NB planes -> per-block exclusive scan -> start[], block sums
__global__ __launch_bounds__(1024) void k_scan_a(const unsigned* __restrict__ hist32, int n,
                                                 int* __restrict__ start,
                                                 int* __restrict__ bsum) {
  __shared__ int wsum[16];
  int t = threadIdx.x, lane = t & 63, w = t >> 6;
  int i = blockIdx.x * 1024 + t;
  int nh = (n + 1) >> 1;
  int stride2 = nh * 2;
  const unsigned short* h16 = (const unsigned short*)hist32;
  int v = 0;
  if (i < n) {
    for (int r = 0; r < NB; ++r) v += h16[(size_t)r * stride2 + i];
  }
  int x = wave_incl_scan(v, lane);
  if (lane == 63) wsum[w] = x;
  __syncthreads();
  if (w == 0 && lane < 16) {
    int s = wsum[lane];
    for (int off = 1; off < 16; off <<= 1) {
      int u = __shfl_up(s, off);
      if (lane >= off) s += u;
    }
    wsum[lane] = s;
  }
  __syncthreads();
  int woff = w ? wsum[w - 1] : 0;
  if (i < n) start[i] = x - v + woff;
  if (t == 1023) bsum[blockIdx.x] = wsum[15];
}

__global__ void k_scan_b(int* __restrict__ bsum, int nb, int* __restrict__ start, int n) {
  int lane = threadIdx.x;  // 64
  int v = (lane < nb) ? bsum[lane] : 0;
  int x = wave_incl_scan(v, lane);
  if (lane < nb) bsum[lane] = x - v;
  if (lane == nb - 1) start[n] = x;
}

// phase C: finalize start; emit per-(block,node) cursor bases
__global__ void k_scan_c(int* __restrict__ start, const int* __restrict__ bsum,
                         const unsigned* __restrict__ hist32, int n,
                         int* __restrict__ cursorp) {
  int i = blockIdx.x * blockDim.x + threadIdx.x;
  if (i >= n) return;
  int nh = (n + 1) >> 1;
  int stride2 = nh * 2;
  const unsigned short* h16 = (const unsigned short*)hist32;
  int s = start[i] + bsum[i >> 10];
  start[i] = s;
  int run = s;
  for (int r = 0; r < NB; ++r) {
    cursorp[(size_t)r * n + i] = run;
    run += h16[(size_t)r * stride2 + i];
  }
}

// same 64-block edge partition as hist; rank via LDS packed-u16 atomic;
// writes one 16B struct per edge — NO global atomics.
__global__ void k_scatter_lds(const int* __restrict__ src, const int* __restrict__ dst,
                              const float* __restrict__ ea, int E, int n,
                              const int* __restrict__ cursorp, Edge2* __restrict__ edges) {
  extern __shared__ unsigned cnt[];
  int nh = (n + 1) >> 1;
  for (int i = threadIdx.x; i < nh; i += blockDim.x) cnt[i] = 0u;
  __syncthreads();
  const int* cur = cursorp + (size_t)blockIdx.x * n;
  int tid = blockIdx.x * blockDim.x + threadIdx.x;
  int stride = gridDim.x * blockDim.x;
  for (int i = tid; i < E; i += stride) {
    int d = dst[i];
    int sh = (d & 1) << 4;
    unsigned old = atomicAdd(&cnt[d >> 1], 1u << sh);
    int rank = (old >> sh) & 0xFFFF;
    int pos = cur[d] + rank;
    unsigned short h0 = __half_as_ushort(__float2half(ea[i * 3 + 0]));
    unsigned short h1 = __half_as_ushort(__float2half(ea[i * 3 + 1]));
    unsigned short h2 = __half_as_ushort(__float2half(ea[i * 3 + 2]));
    Edge2 e;
    e.src = src[i];
    e.dst = d;
    e.e01 = (unsigned)h0 | ((unsigned)h1 << 16);
    e.e2 = (unsigned)h2;
    edges[pos] = e;
  }
}

__device__ __forceinline__ void param_wave(const float* __restrict__ We,
                                           const float* __restrict__ ae,
                                           const float* __restrict__ ea_sum, float invE,
                                           float* __restrict__ P, int lane) {
  float a0 = ae[lane], a1 = ae[64 + lane];
  float p0 = We[0 * 128 + lane] * a0 + We[0 * 128 + 64 + lane] * a1;
  float p1 = We[1 * 128 + lane] * a0 + We[1 * 128 + 64 + lane] * a1;
  float p2 = We[2 * 128 + lane] * a0 + We[2 * 128 + 64 + lane] * a1;
  for (int off = 32; off; off >>= 1) {
    p0 += __shfl_down(p0, off); p1 += __shfl_down(p1, off); p2 += __shfl_down(p2, off);
  }
  if (lane == 0) {
    P[0] = p0; P[1] = p1; P[2] = p2;
    P[3] = ea_sum[0] * invE * p0 + ea_sum[1] * invE * p1 + ea_sum[2] * invE * p2;
  }
}

__global__ void k_param0(const float* __restrict__ We, const float* __restrict__ ae,
                         const float* __restrict__ ea_sum, float invE, float* __restrict__ P,
                         float* __restrict__ scale, float* __restrict__ shift,
                         float* __restrict__ colstats) {
  int t = threadIdx.x;
  if (t < 64) {
    param_wave(We, ae, ea_sum, invE, P, t);
  } else if (t < 192) {
    int c = t - 64;
    scale[c] = 1.f; shift[c] = 0.f;
    colstats[c] = 0.f; colstats[128 + c] = 0.f;
  }
}

__global__ void k_inter(const float* __restrict__ colstatsIn, const float* __restrict__ g,
                        const float* __restrict__ be, float invN,
                        float* __restrict__ scale, float* __restrict__ shift,
                        const float* __restrict__ WeN, const float* __restrict__ aeN,
                        const float* __restrict__ ea_sum, float invE, float* __restrict__ P,
                        float* __restrict__ colstats) {
  int t = threadIdx.x;
  if (t < 64) {
    param_wave(WeN, aeN, ea_sum, invE, P, t);
  } else if (t < 192) {
    int c = t - 64;
    float mu = colstatsIn[c] * invN;
    float var = colstatsIn[128 + c] * invN - mu * mu;
    var = var > 0.f ? var : 0.f;
    float sc = g[c] * rsqrtf(var + 1e-5f);
    scale[c] = sc;
    shift[c] = be[c] - mu * sc;
    colstats[c] = 0.f; colstats[128 + c] = 0.f;
  }
}

// h[N,128] = (X*bnsc+bnsh) @ W, stored as bf16 rows (256 B).  W in LDS,
// 32-row tiles, 4 rows x 4 cols per thread.  Fused al_s/al_d/es epilogue.
__global__ __launch_bounds__(256) void k_gemm2(
    const float* __restrict__ X, const float* __restrict__ Wm,
    const float* __restrict__ bnsc, const float* __restrict__ bnsh,
    const float* __restrict__ as, const float* __restrict__ ad,
    const float* __restrict__ P,
    unsigned* __restrict__ hb, float* __restrict__ al_s, float* __restrict__ al_d,
    float* __restrict__ es, int n) {
  __shared__ float wl[128 * 128];
  __shared__ float xs[32 * 128];
  int t = threadIdx.x;
  for (int i = t; i < 4096; i += 256) ((float4*)wl)[i] = ((const float4*)Wm)[i];
  int c32 = t & 31;
  int c4 = c32 << 2;
  int rq = t >> 5;
  int lane = t & 63;
  float4 av_s = *(const float4*)(as + c4);
  float4 av_d = *(const float4*)(ad + c4);
  float cself = P[3];
  int ntiles = (n + 31) >> 5;
  for (int tile = blockIdx.x; tile < ntiles; tile += gridDim.x) {
    int r0 = tile << 5;
    __syncthreads();
    for (int i = t; i < 1024; i += 256) {
      int rr = i >> 5, cc = i & 31;
      int g = r0 + rr;
      float4 v;
      if (g < n) {
        v = ((const float4*)(X + (size_t)g * 128))[cc];
        float4 sc = ((const float4*)bnsc)[cc];
        float4 sh = ((const float4*)bnsh)[cc];
        v.x = fmaf(v.x, sc.x, sh.x); v.y = fmaf(v.y, sc.y, sh.y);
        v.z = fmaf(v.z, sc.z, sh.z); v.w = fmaf(v.w, sc.w, sh.w);
      } else { v.x = v.y = v.z = v.w = 0.f; }
      ((float4*)xs)[i] = v;
    }
    __syncthreads();
    float4 acc[4];
    for (int r = 0; r < 4; ++r) { acc[r].x = acc[r].y = acc[r].z = acc[r].w = 0.f; }
    const float* xr = xs + (rq << 2) * 128;
#pragma unroll 4
    for (int k = 0; k < 128; ++k) {
      float4 w4 = ((const float4*)wl)[(k << 5) + c32];
#pragma unroll
      for (int r = 0; r < 4; ++r) {
        float xv = xr[r * 128 + k];
        acc[r].x = fmaf(xv, w4.x, acc[r].x);
        acc[r].y = fmaf(xv, w4.y, acc[r].y);
        acc[r].z = fmaf(xv, w4.z, acc[r].z);
        acc[r].w = fmaf(xv, w4.w, acc[r].w);
      }
    }
    int gbase = r0 + (rq << 2);
#pragma unroll
    for (int r = 0; r < 4; ++r) {
      int g = gbase + r;
      float4 o = acc[r];
      if (g < n) {
        unsigned u01 = ((unsigned)f2bf(o.y) << 16) | (unsigned)f2bf(o.x);
        unsigned u23 = ((unsigned)f2bf(o.w) << 16) | (unsigned)f2bf(o.z);
        uint2 uu = {u01, u23};
        *(uint2*)(hb + (size_t)g * 64 + (c32 << 1)) = uu;
      }
      float ps = o.x * av_s.x + o.y * av_s.y + o.z * av_s.z + o.w * av_s.w;
      float pd = o.x * av_d.x + o.y * av_d.y + o.z * av_d.z + o.w * av_d.w;
      for (int off = 16; off; off >>= 1) {
        ps += __shfl_xor(ps, off);
        pd += __shfl_xor(pd, off);
      }
      if ((lane & 31) == 0 && g < n) {
        al_s[g] = ps; al_d[g] = pd;
        float a = ps + pd + cself;
        a = a > 0.f ? a : 0.2f * a;
        es[g] = __expf(a);
      }
    }
  }
}

// flat per-edge: meta[e] = {src, exp(lrelu_0.2(al_s[src] + al_d[dst] + ea.P))}
__global__ __launch_bounds__(256) void k_alpha3(const int4* __restrict__ edges,
                                                const float* __restrict__ al_s,
                                                const float* __restrict__ al_d,
                                                const float* __restrict__ P,
                                                int2* __restrict__ meta, int E) {
  int i = blockIdx.x * blockDim.x + threadIdx.x;
  if (i >= E) return;
  int4 ev = edges[i];
  float e0 = __half2float(__ushort_as_half((unsigned short)(ev.z & 0xFFFF)));
  float e1 = __half2float(__ushort_as_half((unsigned short)(((unsigned)ev.z) >> 16)));
  float e2 = __half2float(__ushort_as_half((unsigned short)(ev.w & 0xFFFF)));
  float a = al_s[ev.x] + al_d[ev.y] + e0 * P[0] + e1 * P[1] + e2 * P[2];
  a = a > 0.f ? a : 0.2f * a;
  int2 mv;
  mv.x = ev.x;
  mv.y = __float_as_int(__expf(a));
  meta[i] = mv;
}

// One wave per node; each 256B row gathered by 16 lanes x uint4, so one
// gather instruction covers FOUR edges (lane-group grp takes edge e+grp).
// Meta via uniform s_loads; per-group row/weight by 3 cndmask selects.
// 8 accumulators/lane = cols 8*sub..8*sub+7; cross-group shfl_xor(16,32)
// combine once per node; pacc stays wave-uniform (sum of all 4 groups'
// weights added by every lane).  Padding: row=i (hot), weight=0.
__global__ __launch_bounds__(256) void k_agg9(const int2* __restrict__ meta,
                                              const int* __restrict__ start,
                                              const unsigned* __restrict__ hb,
                                              const float* __restrict__ es,
                                              const float* __restrict__ bias,
                                              float* __restrict__ y,
                                              float* __restrict__ colsum,
                                              float* __restrict__ colsumsq, int n) {
  int lane = threadIdx.x & 63;
  int w = threadIdx.x >> 6;
  int grp = lane >> 4;   // 0..3: which edge of the quad this lane serves
  int sub = lane & 15;   // position within the row (16 lanes x 16B = 256B)
  int gw = (blockIdx.x * blockDim.x + threadIdx.x) >> 6;
  int nw = (gridDim.x * blockDim.x) >> 6;
  int c0 = (sub << 3) + (grp << 1);  // this lane's 2 output cols
  float2 b2 = ((const float2*)bias)[(sub << 2) + grp];
  float s0 = 0.f, s1 = 0.f, q0 = 0.f, q1 = 0.f;

#define DO_QUAD(EB)                                                          \
  {                                                                          \
    int i0 = (EB), i1 = (EB) + 1, i2 = (EB) + 2, i3 = (EB) + 3;              \
    int2 m0 = meta[i0 < e1 ? i0 : e0];                                       \
    int2 m1 = meta[i1 < e1 ? i1 : e0];                                       \
    int2 m2 = meta[i2 < e1 ? i2 : e0];                                       \
    int2 m3 = meta[i3 < e1 ? i3 : e0];                                       \
    int r0 = i0 < e1 ? m0.x : i;                                             \
    int r1 = i1 < e1 ? m1.x : i;                                             \
    int r2 = i2 < e1 ? m2.x : i;                                             \
    int r3 = i3 < e1 ? m3.x : i;                                             \
    float p0 = i0 < e1 ? __int_as_float(m0.y) : 0.f;                         \
    float p1 = i1 < e1 ? __int_as_float(m1.y) : 0.f;                         \
    float p2 = i2 < e1 ? __int_as_float(m2.y) : 0.f;                         \
    float p3 = i3 < e1 ? __int_as_float(m3.y) : 0.f;                         \
    int rr = grp == 0 ? r0 : grp == 1 ? r1 : grp == 2 ? r2 : r3;             \
    float pp = grp == 0 ? p0 : grp == 1 ? p1 : grp == 2 ? p2 : p3;           \
    uint4 gv = *(const uint4*)(hb + (size_t)rr * 64 + (sub << 2));           \
    pacc += (p0 + p1) + (p2 + p3);                                           \
    aL0 = fmaf(pp, bf_lo(gv.x), aL0); aH0 = fmaf(pp, bf_hi(gv.x), aH0);      \
    aL1 = fmaf(pp, bf_lo(gv.y), aL1); aH1 = fmaf(pp, bf_hi(gv.y), aH1);      \
    aL2 = fmaf(pp, bf_lo(gv.z), aL2); aH2 = fmaf(pp, bf_hi(gv.z), aH2);      \
    aL3 = fmaf(pp, bf_lo(gv.w), aL3); aH3 = fmaf(pp, bf_hi(gv.w), aH3);      \
  }

  for (int i = gw; i < n; i += nw) {
    int e0 = __builtin_amdgcn_readfirstlane(start[i]);
    int e1 = __builtin_amdgcn_readfirstlane(start[i + 1]);
    float eself = es[i];
    uint4 hv = *(const uint4*)(hb + (size_t)i * 64 + (sub << 2));
    float wself = (grp == 0) ? eself : 0.f;  // self-term counted once
    float aL0 = wself * bf_lo(hv.x), aH0 = wself * bf_hi(hv.x);
    float aL1 = wself * bf_lo(hv.y), aH1 = wself * bf_hi(hv.y);
    float aL2 = wself * bf_lo(hv.z), aH2 = wself * bf_hi(hv.z);
    float aL3 = wself * bf_lo(hv.w), aH3 = wself * bf_hi(hv.w);
    float pacc = 0.f;
    int e = e0;
    for (; e + 8 <= e1; e += 8) {  // two quads -> two gathers in flight
      DO_QUAD(e);
      DO_QUAD(e + 4);
    }
    for (; e < e1; e += 4) DO_QUAD(e);
    // combine the 4 lane-groups (bits 4,5 of lane)
    aL0 += __shfl_xor(aL0, 16); aL0 += __shfl_xor(aL0, 32);
    aH0 += __shfl_xor(aH0, 16); aH0 += __shfl_xor(aH0, 32);
    aL1 += __shfl_xor(aL1, 16); aL1 += __shfl_xor(aL1, 32);
    aH1 += __shfl_xor(aH1, 16); aH1 += __shfl_xor(aH1, 32);
    aL2 += __shfl_xor(aL2, 16); aL2 += __shfl_xor(aL2, 32);
    aH2 += __shfl_xor(aH2, 16); aH2 += __shfl_xor(aH2, 32);
    aL3 += __shfl_xor(aL3, 16); aL3 += __shfl_xor(aL3, 32);
    aH3 += __shfl_xor(aH3, 16); aH3 += __shfl_xor(aH3, 32);
    float inv = 1.0f / (eself + pacc + 1e-16f);
    float o0 = grp == 0 ? aL0 : grp == 1 ? aL1 : grp == 2 ? aL2 : aL3;
    float o1 = grp == 0 ? aH0 : grp == 1 ? aH1 : grp == 2 ? aH2 : aH3;
    o0 = fmaf(o0, inv, b2.x);
    o1 = fmaf(o1, inv, b2.y);
    o0 = o0 > 0.f ? o0 : 0.01f * o0;
    o1 = o1 > 0.f ? o1 : 0.01f * o1;
    float2 o2 = {o0, o1};
    *(float2*)(y + (size_t)i * 128 + c0) = o2;
    s0 += o0; s1 += o1;
    q0 = fmaf(o0, o0, q0); q1 = fmaf(o1, o1, q1);
  }
#undef DO_QUAD
  __shared__ float red[4][4][64];
  red[0][w][lane] = s0; red[1][w][lane] = s1; red[2][w][lane] = q0; red[3][w][lane] = q1;
  __syncthreads();
  if (w == 0) {
    for (int ww = 1; ww < 4; ++ww) {
      s0 += red[0][ww][lane]; s1 += red[1][ww][lane];
      q0 += red[2][ww][lane]; q1 += red[3][ww][lane];
    }
    atomicAdd(&colsum[c0], s0);
    atomicAdd(&colsum[c0 + 1], s1);
    atomicAdd(&colsumsq[c0], q0);
    atomicAdd(&colsumsq[c0 + 1], q1);
  }
}

// final BN: compute scale/shift from colstats in-block, then apply y -> out
__global__ __launch_bounds__(256) void k_bnapply_final(
    const float4* __restrict__ yin, const float* __restrict__ colstats,
    const float* __restrict__ g, const float* __restrict__ be, float invN,
    float4* __restrict__ yout, int total4) {
  __shared__ float sc_s[128], sh_s[128];
  int t = threadIdx.x;
  if (t < 128) {
    float mu = colstats[t] * invN;
    float var = colstats[128 + t] * invN - mu * mu;
    var = var > 0.f ? var : 0.f;
    float sc = g[t] * rsqrtf(var + 1e-5f);
    sc_s[t] = sc;
    sh_s[t] = be[t] - mu * sc;
  }
  __syncthreads();
  for (int i = blockIdx.x * blockDim.x + t; i < total4; i += gridDim.x * blockDim.x) {
    int c4 = (i & 31) << 2;
    float4 v = yin[i];
    v.x = fmaf(v.x, sc_s[c4 + 0], sh_s[c4 + 0]);
    v.y = fmaf(v.y, sc_s[c4 + 1], sh_s[c4 + 1]);
    v.z = fmaf(v.z, sc_s[c4 + 2], sh_s[c4 + 2]);
    v.w = fmaf(v.w, sc_s[c4 + 3], sh_s[c4 + 3]);
    yout[i] = v;
  }
}

extern "C" void kernel_launch(void* const* d_in, const int* in_sizes, int n_in,
                              void* d_out, int out_size, void* d_ws, size_t ws_size,
                              hipStream_t stream) {
  const float* x = (const float*)d_in[0];
  const int* eidx = (const int*)d_in[1];
  const float* ea = (const float*)d_in[3];
  const int H = 128;
  const int N = in_sizes[0] / H;
  const int E = in_sizes[1] / 2;
  const int* srcIdx = eidx;
  const int* dstIdx = eidx + E;
  const int nh = (N + 1) >> 1;

  char* ws = (char*)d_ws;
  size_t off = 0;
  auto alloc = [&](size_t bytes) -> void* {
    void* p = ws + off;
    off = (off + bytes + 255) & ~(size_t)255;
    return p;
  };
  Edge2* edges = (Edge2*)alloc((size_t)E * sizeof(Edge2));
  int2* meta = (int2*)alloc((size_t)E * sizeof(int2));  // {src, pexp}
  unsigned* hb = (unsigned*)alloc((size_t)N * 64 * sizeof(unsigned));  // bf16 h
  float* y = (float*)alloc((size_t)N * H * sizeof(float));
  float* al_s = (float*)alloc((size_t)N * sizeof(float));
  float* al_d = (float*)alloc((size_t)N * sizeof(float));
  float* es = (float*)alloc((size_t)N * sizeof(float));
  unsigned* hist32 = (unsigned*)alloc((size_t)NB * nh * sizeof(unsigned));
  int* cursorp = (int*)alloc((size_t)NB * N * sizeof(int));
  int* start = (int*)alloc((size_t)(N + 1) * sizeof(int));
  int* bsum = (int*)alloc(64 * sizeof(int));
  float* colstats = (float*)alloc(256 * sizeof(float));
  float* colsum = colstats;
  float* colsumsq = colstats + 128;
  float* scale = (float*)alloc(128 * sizeof(float));
  float* shift = (float*)alloc(128 * sizeof(float));
  float* ea_sum = (float*)alloc(64 * sizeof(float));
  float* P = (float*)alloc(16 * sizeof(float));

  const int nb = (N + 1023) / 1024;  // <= 64
  const float invE = 1.0f / (float)E;
  const float invN = 1.0f / (float)N;
  const size_t ldsBytes = (size_t)nh * sizeof(unsigned);  // 100 KB @ N=50k

  // ---- setup: CSR sort with LDS-only atomics ----
  hipMemsetAsync(ea_sum, 0, 64 * sizeof(float), stream);
  k_hist_lds<<<NB, 256, ldsBytes, stream>>>(dstIdx, ea, E, N, hist32, ea_sum);
  k_scan_a<<<nb, 1024, 0, stream>>>(hist32, N, start, bsum);
  k_scan_b<<<1, 64, 0, stream>>>(bsum, nb, start, N);
  k_scan_c<<<(N + 255) / 256, 256, 0, stream>>>(start, bsum, hist32, N, cursorp);
  k_scatter_lds<<<NB, 256, ldsBytes, stream>>>(srcIdx, dstIdx, ea, E, N, cursorp, edges);

  // layer parameter pointers
  const float* Wl[3]; const float* asl[3]; const float* adl[3]; const float* Wel[3];
  const float* ael[3]; const float* bl[3]; const float* gl[3]; const float* bel[3];
  for (int l = 0; l < 3; ++l) {
    Wl[l] = (const float*)d_in[4 + 8 * l + 0];
    asl[l] = (const float*)d_in[4 + 8 * l + 1];
    adl[l] = (const float*)d_in[4 + 8 * l + 2];
    Wel[l] = (const float*)d_in[4 + 8 * l + 3];
    ael[l] = (const float*)d_in[4 + 8 * l + 4];
    bl[l] = (const float*)d_in[4 + 8 * l + 5];
    gl[l] = (const float*)d_in[4 + 8 * l + 6];
    bel[l] = (const float*)d_in[4 + 8 * l + 7];
  }

  k_param0<<<1, 192, 0, stream>>>(Wel[0], ael[0], ea_sum, invE, P, scale, shift, colstats);

  const float* X = x;
  for (int l = 0; l < 3; ++l) {
    k_gemm2<<<512, 256, 0, stream>>>(X, Wl[l], scale, shift, asl[l], adl[l], P,
                                     hb, al_s, al_d, es, N);
    k_alpha3<<<(E + 255) / 256, 256, 0, stream>>>((const int4*)edges, al_s, al_d, P,
                                                  meta, E);
    k_agg9<<<2048, 256, 0, stream>>>(meta, start, hb, es, bl[l], y,
                                     colsum, colsumsq, N);
    if (l < 2) {
      k_inter<<<1, 192, 0, stream>>>(colstats, gl[l], bel[l], invN, scale, shift,
                                     Wel[l + 1], ael[l + 1], ea_sum, invE, P, colstats);
    }
    X = y;
  }
  k_bnapply_final<<<384, 256, 0, stream>>>((const float4*)y, colstats, gl[2], bel[2], invN,
                                           (float4*)d_out, N * 32);
}